// Round 2
// baseline (687.707 us; speedup 1.0000x reference)
//
#include <hip/hip_runtime.h>
#include <math.h>

namespace {

constexpr int B = 2048;
constexpr int C = 20000;
constexpr int D = 512;
constexpr int LMAX = 8;
constexpr int NS = 32;          // number of column-split groups
constexpr int BM = 64;          // rows per workgroup
constexpr int BN = 64;          // cols per tile
constexpr int KT = 32;          // K-step
constexpr int LDP = 68;         // padded leading dim for K-major LDS tiles
constexpr int NTILES = (C + BN - 1) / BN;   // 313 (last tile has 32 valid cols)

constexpr float S_SCALE = 30.0f;
constexpr float COS_M = 0.87758256189037271f;   // cos(0.5)
constexpr float SIN_M = 0.47942553860420301f;   // sin(0.5)
constexpr float TH    = -0.87758256189037271f;  // cos(pi - 0.5)
constexpr float MM    = 0.23971276930210156f;   // sin(pi - 0.5) * 0.5

__device__ __forceinline__ float wave_sum(float v) {
    #pragma unroll
    for (int off = 1; off < 64; off <<= 1) v += __shfl_xor(v, off, 64);
    return v;
}

// one wave per row: sqrt(sum(x^2)) over D=512
__global__ void norm_kernel(const float* __restrict__ x, float* __restrict__ out, int rows) {
    const int wave = threadIdx.x >> 6, lane = threadIdx.x & 63;
    const int row = blockIdx.x * 4 + wave;
    if (row >= rows) return;
    const float4* p = reinterpret_cast<const float4*>(x + (size_t)row * D);
    const float4 a = p[lane * 2 + 0];
    const float4 b = p[lane * 2 + 1];
    float s = a.x*a.x + a.y*a.y + a.z*a.z + a.w*a.w
            + b.x*b.x + b.y*b.y + b.z*b.z + b.w*b.w;
    s = wave_sum(s);
    if (lane == 0) out[row] = sqrtf(s);
}

// Fused GEMM + online-softmax partials over plain logits o = s*cos_sim.
// grid = (B/BM) x NS. WG (bx,by) processes col-tiles {by, by+NS, ...}.
// Writes per-(row, by) partial (max, sumexp) to pm/pZ.
__global__ __launch_bounds__(256) void
gemm_softmax_kernel(const float* __restrict__ f, const float* __restrict__ w,
                    const float* __restrict__ fn, const float* __restrict__ wn,
                    float* __restrict__ pm, float* __restrict__ pZ)
{
    __shared__ float sfT[KT][LDP];   // f tile, K-major
    __shared__ float swT[KT][LDP];   // w tile, K-major
    __shared__ float sfn[BM];

    const int tid = threadIdx.x;
    const int bx = blockIdx.x;       // row block
    const int by = blockIdx.y;       // col group
    const int tx = tid & 15;         // 16x16 thread grid
    const int tyg = tid >> 4;
    const int r0 = tyg * 4;          // this thread's 4 rows (local)

    if (tid < BM) sfn[tid] = fn[bx * BM + tid];

    const int lrow = tid >> 3;       // 0..31 : staging row/col index
    const int k4 = (tid & 7) * 4;    // 0..28 : staging k offset

    float m[4], Z[4];
    #pragma unroll
    for (int i = 0; i < 4; ++i) { m[i] = -INFINITY; Z[i] = 0.0f; }

    for (int tile = by; tile < NTILES; tile += NS) {
        const int c0 = tile * BN;
        float acc[4][4];
        #pragma unroll
        for (int i = 0; i < 4; ++i)
            #pragma unroll
            for (int j = 0; j < 4; ++j) acc[i][j] = 0.0f;

        for (int k0 = 0; k0 < D; k0 += KT) {
            __syncthreads();
            {   // stage f tile (transposed to K-major)
                const float4 v0 = *reinterpret_cast<const float4*>(
                    &f[(size_t)(bx * BM + lrow) * D + k0 + k4]);
                const float4 v1 = *reinterpret_cast<const float4*>(
                    &f[(size_t)(bx * BM + lrow + 32) * D + k0 + k4]);
                sfT[k4+0][lrow] = v0.x; sfT[k4+1][lrow] = v0.y;
                sfT[k4+2][lrow] = v0.z; sfT[k4+3][lrow] = v0.w;
                sfT[k4+0][lrow+32] = v1.x; sfT[k4+1][lrow+32] = v1.y;
                sfT[k4+2][lrow+32] = v1.z; sfT[k4+3][lrow+32] = v1.w;
            }
            {   // stage w tile (transposed, zero-padded past C)
                const int c_a = c0 + lrow;
                const int c_b = c0 + lrow + 32;
                float4 v0 = make_float4(0.f,0.f,0.f,0.f);
                float4 v1 = make_float4(0.f,0.f,0.f,0.f);
                if (c_a < C) v0 = *reinterpret_cast<const float4*>(&w[(size_t)c_a * D + k0 + k4]);
                if (c_b < C) v1 = *reinterpret_cast<const float4*>(&w[(size_t)c_b * D + k0 + k4]);
                swT[k4+0][lrow] = v0.x; swT[k4+1][lrow] = v0.y;
                swT[k4+2][lrow] = v0.z; swT[k4+3][lrow] = v0.w;
                swT[k4+0][lrow+32] = v1.x; swT[k4+1][lrow+32] = v1.y;
                swT[k4+2][lrow+32] = v1.z; swT[k4+3][lrow+32] = v1.w;
            }
            __syncthreads();
            #pragma unroll
            for (int k = 0; k < KT; ++k) {
                const float4 a = *reinterpret_cast<const float4*>(&sfT[k][r0]);
                const float4 b = *reinterpret_cast<const float4*>(&swT[k][tx * 4]);
                acc[0][0] += a.x * b.x; acc[0][1] += a.x * b.y;
                acc[0][2] += a.x * b.z; acc[0][3] += a.x * b.w;
                acc[1][0] += a.y * b.x; acc[1][1] += a.y * b.y;
                acc[1][2] += a.y * b.z; acc[1][3] += a.y * b.w;
                acc[2][0] += a.z * b.x; acc[2][1] += a.z * b.y;
                acc[2][2] += a.z * b.z; acc[2][3] += a.z * b.w;
                acc[3][0] += a.w * b.x; acc[3][1] += a.w * b.y;
                acc[3][2] += a.w * b.z; acc[3][3] += a.w * b.w;
            }
        }
        // fold this tile into running (m, Z)
        const int cb = c0 + tx * 4;
        float wnv[4];
        #pragma unroll
        for (int j = 0; j < 4; ++j) wnv[j] = (cb + j < C) ? wn[cb + j] : 1.0f;
        #pragma unroll
        for (int i = 0; i < 4; ++i) {
            const float fni = sfn[r0 + i];
            #pragma unroll
            for (int j = 0; j < 4; ++j) {
                float o;
                if (cb + j < C) {
                    const float denom = fmaxf(fni * wnv[j], 1e-8f);
                    o = S_SCALE * acc[i][j] / denom;
                } else {
                    o = -INFINITY;   // padded column: contributes 0 to Z
                }
                const float mn = fmaxf(m[i], o);
                Z[i] = Z[i] * __expf(m[i] - mn) + __expf(o - mn);
                m[i] = mn;
            }
        }
    }

    // combine (m,Z) across the 16 lanes (tx) sharing each row — all within one wave
    #pragma unroll
    for (int i = 0; i < 4; ++i) {
        float mi = m[i], Zi = Z[i];
        #pragma unroll
        for (int off = 1; off < 16; off <<= 1) {
            const float mo = __shfl_xor(mi, off, 64);
            const float Zo = __shfl_xor(Zi, off, 64);
            const float mn = fmaxf(mi, mo);
            Zi = Zi * __expf(mi - mn) + Zo * __expf(mo - mn);
            mi = mn;
        }
        m[i] = mi; Z[i] = Zi;
    }
    if (tx == 0) {
        #pragma unroll
        for (int i = 0; i < 4; ++i) {
            const int row = bx * BM + r0 + i;
            pm[(size_t)row * NS + by] = m[i];
            pZ[(size_t)row * NS + by] = Z[i];
        }
    }
}

// One wave (64 threads) per row: combine split partials, recompute the <=8
// target logits exactly, apply ArcFace margin, correct Z, emit per-row loss.
__global__ void finalize_kernel(const float* __restrict__ f, const float* __restrict__ w,
                                const float* __restrict__ fn, const float* __restrict__ wn,
                                const int* __restrict__ pinds, const int* __restrict__ lengths,
                                const float* __restrict__ pm, const float* __restrict__ pZ,
                                float* __restrict__ loss)
{
    const int b = blockIdx.x;
    const int lane = threadIdx.x;

    // combine the NS partials (finite sentinel avoids -inf - -inf NaN)
    float mp = -3.0e38f, Zp = 0.0f;
    if (lane < NS) { mp = pm[(size_t)b * NS + lane]; Zp = pZ[(size_t)b * NS + lane]; }
    #pragma unroll
    for (int off = 1; off < 64; off <<= 1) {
        const float mo = __shfl_xor(mp, off, 64);
        const float Zo = __shfl_xor(Zp, off, 64);
        const float mn = fmaxf(mp, mo);
        Zp = Zp * __expf(mp - mn) + Zo * __expf(mo - mn);
        mp = mn;
    }
    const float M = mp;
    const float Ztot = Zp;

    const float4* fp = reinterpret_cast<const float4*>(f + (size_t)b * D);
    const float4 a0 = fp[lane * 2 + 0];
    const float4 a1 = fp[lane * 2 + 1];
    const float fnb = fn[b];
    const int len = lengths[b];

    float opl[LMAX], ops[LMAX];
    int cs[LMAX];
    #pragma unroll
    for (int j = 0; j < LMAX; ++j) {
        const int c = pinds[(size_t)b * LMAX + j];
        cs[j] = c;
        const float4* wp = reinterpret_cast<const float4*>(w + (size_t)c * D);
        const float4 w0 = wp[lane * 2 + 0];
        const float4 w1 = wp[lane * 2 + 1];
        float d = a0.x*w0.x + a0.y*w0.y + a0.z*w0.z + a0.w*w0.w
                + a1.x*w1.x + a1.y*w1.y + a1.z*w1.z + a1.w*w1.w;
        d = wave_sum(d);
        const float cosv = d / fmaxf(fnb * wn[c], 1e-8f);
        const float sine = sqrtf(fminf(fmaxf(1.0f - cosv * cosv, 0.0f), 1.0f));
        float phi = cosv * COS_M - sine * SIN_M;
        phi = (cosv > TH) ? phi : (cosv - MM);
        opl[j] = S_SCALE * cosv;
        ops[j] = S_SCALE * phi;
    }

    // correct Z for unique positive classes, then ragged CE
    float Zc = Ztot;
    for (int j = 0; j < len; ++j) {
        bool dup = false;
        for (int jj = 0; jj < j; ++jj) dup = dup || (cs[jj] == cs[j]);
        if (!dup) Zc += expf(ops[j] - M) - expf(opl[j] - M);
    }
    const float lZ = logf(Zc);
    float acc = 0.0f;
    for (int j = 0; j < len; ++j) acc += (M + lZ - ops[j]);
    const float Lf = (float)len;
    if (lane == 0) loss[b] = acc / (Lf * Lf);
}

__global__ void reduce_kernel(const float* __restrict__ loss, float* __restrict__ out) {
    __shared__ float sdata[256];
    const int t = threadIdx.x;
    float s = 0.0f;
    for (int i = t; i < B; i += 256) s += loss[i];
    sdata[t] = s;
    __syncthreads();
    for (int off = 128; off > 0; off >>= 1) {
        if (t < off) sdata[t] += sdata[t + off];
        __syncthreads();
    }
    if (t == 0) out[0] = sdata[0] * (1.0f / (float)B);
}

} // anonymous namespace

extern "C" void kernel_launch(void* const* d_in, const int* in_sizes, int n_in,
                              void* d_out, int out_size, void* d_ws, size_t ws_size,
                              hipStream_t stream) {
    const float* f   = (const float*)d_in[0];
    // d_in[1] = labels [B,C] — not needed (reconstructed from pinds/lengths)
    const float* w   = (const float*)d_in[2];
    const int* pinds = (const int*)d_in[3];
    const int* lens  = (const int*)d_in[4];
    float* out = (float*)d_out;

    float* wsf  = (float*)d_ws;
    float* wn   = wsf;                     // C
    float* fn   = wn + C;                  // B
    float* pm   = fn + B;                  // B*NS
    float* pZ   = pm + (size_t)B * NS;     // B*NS
    float* loss = pZ + (size_t)B * NS;     // B

    norm_kernel<<<dim3(B / 4), 256, 0, stream>>>(f, fn, B);
    norm_kernel<<<dim3(C / 4), 256, 0, stream>>>(w, wn, C);
    gemm_softmax_kernel<<<dim3(B / BM, NS), 256, 0, stream>>>(f, w, fn, wn, pm, pZ);
    finalize_kernel<<<dim3(B), 64, 0, stream>>>(f, w, fn, wn, pinds, lens, pm, pZ, loss);
    reduce_kernel<<<dim3(1), 256, 0, stream>>>(loss, out);
}

// Round 4
// 241.925 us; speedup vs baseline: 2.8426x; 2.8426x over previous
//
#include <hip/hip_runtime.h>
#include <math.h>

namespace {

constexpr int B = 2048;
constexpr int C = 20000;
constexpr int D = 512;
constexpr int LMAX = 8;

// ---------------- MFMA path geometry ----------------
constexpr int BMt = 128, BNt = 128, BKt = 64;
constexpr int NROWT = B / BMt;               // 16 row tiles
constexpr int NPAN  = (C + BNt - 1) / BNt;   // 157 col panels (last has 32 valid)
constexpr int KST   = D / BKt;               // 8 K-steps
constexpr int CHUNKS = 2048;                 // f16x8 (16B) slots per k-step block = 32KB

// ---------------- fp32 fallback geometry ----------------
constexpr int NSOLD = 32;
constexpr int BM = 64, BN = 64, KT = 32, LDP = 68;
constexpr int NTILES = (C + BN - 1) / BN;

constexpr float S_SCALE = 30.0f;
constexpr float COS_M = 0.87758256189037271f;   // cos(0.5)
constexpr float SIN_M = 0.47942553860420301f;   // sin(0.5)
constexpr float TH    = -0.87758256189037271f;  // cos(pi - 0.5)
constexpr float MM    = 0.23971276930210156f;   // sin(pi - 0.5) * 0.5

typedef float f32x16 __attribute__((ext_vector_type(16)));
typedef _Float16 f16x8 __attribute__((ext_vector_type(8)));

__device__ __forceinline__ void mfma_16(f32x16& acc, f16x8 a, f16x8 b) {
    acc = __builtin_amdgcn_mfma_f32_32x32x16_f16(a, b, acc, 0, 0, 0);
}

__device__ __forceinline__ float wave_sum(float v) {
    #pragma unroll
    for (int off = 1; off < 64; off <<= 1) v += __shfl_xor(v, off, 64);
    return v;
}

// split x ~= hi + lo in f16 (RNE both stages)
__device__ __forceinline__ void split8(const float4 x0, const float4 x1, f16x8& h, f16x8& l) {
    const float xs[8] = {x0.x, x0.y, x0.z, x0.w, x1.x, x1.y, x1.z, x1.w};
    #pragma unroll
    for (int j = 0; j < 8; ++j) {
        const _Float16 hj = (_Float16)xs[j];
        h[j] = hj;
        l[j] = (_Float16)(xs[j] - (float)hj);
    }
}

// one wave per row: sqrt(sum(x^2)) over D=512
__global__ void norm_kernel(const float* __restrict__ x, float* __restrict__ out, int rows) {
    const int wave = threadIdx.x >> 6, lane = threadIdx.x & 63;
    const int row = blockIdx.x * 4 + wave;
    if (row >= rows) return;
    const float4* p = reinterpret_cast<const float4*>(x + (size_t)row * D);
    const float4 a = p[lane * 2 + 0];
    const float4 b = p[lane * 2 + 1];
    float s = a.x*a.x + a.y*a.y + a.z*a.z + a.w*a.w
            + b.x*b.x + b.y*b.y + b.z*b.z + b.w*b.w;
    s = wave_sum(s);
    if (lane == 0) out[row] = sqrtf(s);
}

// Pack f into fragment-linear f16 hi/lo panels.
// Layout: Ap[rowtile][kstep][chunk][lane] (f16x8). chunk = h*16 + m_frag*4 + k16.
// Slot (chunk,lane): row = m_frag*32+(lane&31), k = k16*16 + (lane>>5)*8 .. +8.
__global__ void pack_a_kernel(const float* __restrict__ f, f16x8* __restrict__ Ap) {
    const int bx = blockIdx.x;   // row tile
    const int s  = blockIdx.y;   // k-step
    const int t  = threadIdx.x;  // 256
    f16x8* blk = Ap + (size_t)(bx * KST + s) * CHUNKS;
    #pragma unroll
    for (int i = 0; i < 4; ++i) {
        const int v = i * 256 + t;           // hi slot id 0..1023
        const int q = v >> 6;                // chunk 0..15 = m_frag*4 + k16
        const int l = v & 63;
        const int row = bx * BMt + (q >> 2) * 32 + (l & 31);
        const int k   = s * BKt + (q & 3) * 16 + (l >> 5) * 8;
        const float4 x0 = *reinterpret_cast<const float4*>(&f[(size_t)row * D + k]);
        const float4 x1 = *reinterpret_cast<const float4*>(&f[(size_t)row * D + k + 4]);
        f16x8 hv, lv;
        split8(x0, x1, hv, lv);
        blk[q * 64 + l] = hv;
        blk[(16 + q) * 64 + l] = lv;
    }
}

// Same for W columns (B operand); zero-fill cols >= C.
__global__ void pack_b_kernel(const float* __restrict__ w, f16x8* __restrict__ Bp) {
    const int pan = blockIdx.x;  // panel
    const int s   = blockIdx.y;  // k-step
    const int t   = threadIdx.x;
    f16x8* blk = Bp + (size_t)(pan * KST + s) * CHUNKS;
    #pragma unroll
    for (int i = 0; i < 4; ++i) {
        const int v = i * 256 + t;
        const int q = v >> 6;
        const int l = v & 63;
        const int col = pan * BNt + (q >> 2) * 32 + (l & 31);
        const int k   = s * BKt + (q & 3) * 16 + (l >> 5) * 8;
        f16x8 hv = (f16x8)0, lv = (f16x8)0;
        if (col < C) {
            const float4 x0 = *reinterpret_cast<const float4*>(&w[(size_t)col * D + k]);
            const float4 x1 = *reinterpret_cast<const float4*>(&w[(size_t)col * D + k + 4]);
            split8(x0, x1, hv, lv);
        }
        blk[q * 64 + l] = hv;
        blk[(16 + q) * 64 + l] = lv;
    }
}

// MFMA GEMM (f16 split-3) + fused online-softmax partials.
// grid = (16 rowtiles, 157 panels), 256 threads (4 waves, 2x2 wave grid, 64x64 per wave).
__global__ __launch_bounds__(256) void
gemm_mfma_kernel(const f16x8* __restrict__ Ap, const f16x8* __restrict__ Bp,
                 const float* __restrict__ fn, const float* __restrict__ wn,
                 float* __restrict__ pm, float* __restrict__ pZ)
{
    __shared__ f16x8 sA[CHUNKS];   // 32KB
    __shared__ f16x8 sB[CHUNKS];   // 32KB
    const int tid  = threadIdx.x;
    const int lane = tid & 63;
    const int w    = tid >> 6;
    const int wm   = w >> 1;        // 0..1
    const int wnn  = w & 1;         // 0..1
    const int bx = blockIdx.x, by = blockIdx.y;
    const f16x8* Ab = Ap + (size_t)(bx * KST) * CHUNKS;
    const f16x8* Bb = Bp + (size_t)(by * KST) * CHUNKS;

    f32x16 acc00, acc01, acc10, acc11;
    #pragma unroll
    for (int i = 0; i < 16; ++i) { acc00[i] = 0.f; acc01[i] = 0.f; acc10[i] = 0.f; acc11[i] = 0.f; }

    for (int s = 0; s < KST; ++s) {
        __syncthreads();
        f16x8 tmp[8];
        #pragma unroll
        for (int i = 0; i < 8; ++i) tmp[i] = Ab[(size_t)s * CHUNKS + i * 256 + tid];
        #pragma unroll
        for (int i = 0; i < 8; ++i) sA[i * 256 + tid] = tmp[i];
        #pragma unroll
        for (int i = 0; i < 8; ++i) tmp[i] = Bb[(size_t)s * CHUNKS + i * 256 + tid];
        #pragma unroll
        for (int i = 0; i < 8; ++i) sB[i * 256 + tid] = tmp[i];
        __syncthreads();
        #pragma unroll
        for (int k16 = 0; k16 < 4; ++k16) {
            const f16x8 ah0 = sA[((wm * 2 + 0) * 4 + k16) * 64 + lane];
            const f16x8 ah1 = sA[((wm * 2 + 1) * 4 + k16) * 64 + lane];
            const f16x8 al0 = sA[(16 + (wm * 2 + 0) * 4 + k16) * 64 + lane];
            const f16x8 al1 = sA[(16 + (wm * 2 + 1) * 4 + k16) * 64 + lane];
            const f16x8 bh0 = sB[((wnn * 2 + 0) * 4 + k16) * 64 + lane];
            const f16x8 bh1 = sB[((wnn * 2 + 1) * 4 + k16) * 64 + lane];
            const f16x8 bl0 = sB[(16 + (wnn * 2 + 0) * 4 + k16) * 64 + lane];
            const f16x8 bl1 = sB[(16 + (wnn * 2 + 1) * 4 + k16) * 64 + lane];
            mfma_16(acc00, ah0, bh0); mfma_16(acc01, ah0, bh1);
            mfma_16(acc10, ah1, bh0); mfma_16(acc11, ah1, bh1);
            mfma_16(acc00, ah0, bl0); mfma_16(acc01, ah0, bl1);
            mfma_16(acc10, ah1, bl0); mfma_16(acc11, ah1, bl1);
            mfma_16(acc00, al0, bh0); mfma_16(acc01, al0, bh1);
            mfma_16(acc10, al1, bh0); mfma_16(acc11, al1, bh1);
        }
    }

    // ---- epilogue: logits -> per-(row, panel) online (max, sumexp) partial ----
    __syncthreads();
    float* sRed = reinterpret_cast<float*>(sA);   // [128 rows][2 wnn][2] = 2KB (reuse)
    const int half = lane >> 5, l31 = lane & 31;
    const int gc0 = by * BNt + wnn * 64 + l31;
    const int gc1 = gc0 + 32;
    const float wnv0 = (gc0 < C) ? wn[gc0] : 1.0f;
    const float wnv1 = (gc1 < C) ? wn[gc1] : 1.0f;

#define EPI_M(A0, A1, M)                                                            \
    {                                                                               \
        _Pragma("unroll")                                                           \
        for (int r = 0; r < 16; ++r) {                                              \
            const int row_in = (r & 3) + 8 * (r >> 2) + 4 * half;                   \
            const int lrow = wm * 64 + (M) * 32 + row_in;                           \
            const float fnv = fn[bx * BMt + lrow];                                  \
            float o0 = (gc0 < C) ? (S_SCALE * (A0)[r] / fmaxf(fnv * wnv0, 1e-8f))   \
                                 : -3.0e38f;                                        \
            float o1 = (gc1 < C) ? (S_SCALE * (A1)[r] / fmaxf(fnv * wnv1, 1e-8f))   \
                                 : -3.0e38f;                                        \
            float mx = fmaxf(o0, o1);                                               \
            _Pragma("unroll")                                                       \
            for (int off = 1; off < 32; off <<= 1)                                  \
                mx = fmaxf(mx, __shfl_xor(mx, off, 64));                            \
            float Zl = __expf(o0 - mx) + __expf(o1 - mx);                           \
            _Pragma("unroll")                                                       \
            for (int off = 1; off < 32; off <<= 1)                                  \
                Zl += __shfl_xor(Zl, off, 64);                                      \
            if (l31 == 0) {                                                         \
                sRed[(lrow * 2 + wnn) * 2 + 0] = mx;                                \
                sRed[(lrow * 2 + wnn) * 2 + 1] = Zl;                                \
            }                                                                       \
        }                                                                           \
    }
    EPI_M(acc00, acc01, 0)
    EPI_M(acc10, acc11, 1)
#undef EPI_M

    __syncthreads();
    if (tid < BMt) {
        const float ma = sRed[(tid * 2 + 0) * 2 + 0], Za = sRed[(tid * 2 + 0) * 2 + 1];
        const float mb = sRed[(tid * 2 + 1) * 2 + 0], Zb = sRed[(tid * 2 + 1) * 2 + 1];
        const float mn = fmaxf(ma, mb);
        const float Zt = Za * __expf(ma - mn) + Zb * __expf(mb - mn);
        pm[(size_t)(bx * BMt + tid) * NPAN + by] = mn;
        pZ[(size_t)(bx * BMt + tid) * NPAN + by] = Zt;
    }
}

// ---------------- fp32 fallback GEMM (proven R2 path) ----------------
__global__ __launch_bounds__(256) void
gemm_softmax_kernel(const float* __restrict__ f, const float* __restrict__ w,
                    const float* __restrict__ fn, const float* __restrict__ wn,
                    float* __restrict__ pm, float* __restrict__ pZ)
{
    __shared__ float sfT[KT][LDP];
    __shared__ float swT[KT][LDP];
    __shared__ float sfn[BM];

    const int tid = threadIdx.x;
    const int bx = blockIdx.x;
    const int by = blockIdx.y;
    const int tx = tid & 15;
    const int tyg = tid >> 4;
    const int r0 = tyg * 4;

    if (tid < BM) sfn[tid] = fn[bx * BM + tid];

    const int lrow = tid >> 3;
    const int k4 = (tid & 7) * 4;

    float m[4], Z[4];
    #pragma unroll
    for (int i = 0; i < 4; ++i) { m[i] = -INFINITY; Z[i] = 0.0f; }

    for (int tile = by; tile < NTILES; tile += NSOLD) {
        const int c0 = tile * BN;
        float acc[4][4];
        #pragma unroll
        for (int i = 0; i < 4; ++i)
            #pragma unroll
            for (int j = 0; j < 4; ++j) acc[i][j] = 0.0f;

        for (int k0 = 0; k0 < D; k0 += KT) {
            __syncthreads();
            {
                const float4 v0 = *reinterpret_cast<const float4*>(
                    &f[(size_t)(bx * BM + lrow) * D + k0 + k4]);
                const float4 v1 = *reinterpret_cast<const float4*>(
                    &f[(size_t)(bx * BM + lrow + 32) * D + k0 + k4]);
                sfT[k4+0][lrow] = v0.x; sfT[k4+1][lrow] = v0.y;
                sfT[k4+2][lrow] = v0.z; sfT[k4+3][lrow] = v0.w;
                sfT[k4+0][lrow+32] = v1.x; sfT[k4+1][lrow+32] = v1.y;
                sfT[k4+2][lrow+32] = v1.z; sfT[k4+3][lrow+32] = v1.w;
            }
            {
                const int c_a = c0 + lrow;
                const int c_b = c0 + lrow + 32;
                float4 v0 = make_float4(0.f,0.f,0.f,0.f);
                float4 v1 = make_float4(0.f,0.f,0.f,0.f);
                if (c_a < C) v0 = *reinterpret_cast<const float4*>(&w[(size_t)c_a * D + k0 + k4]);
                if (c_b < C) v1 = *reinterpret_cast<const float4*>(&w[(size_t)c_b * D + k0 + k4]);
                swT[k4+0][lrow] = v0.x; swT[k4+1][lrow] = v0.y;
                swT[k4+2][lrow] = v0.z; swT[k4+3][lrow] = v0.w;
                swT[k4+0][lrow+32] = v1.x; swT[k4+1][lrow+32] = v1.y;
                swT[k4+2][lrow+32] = v1.z; swT[k4+3][lrow+32] = v1.w;
            }
            __syncthreads();
            #pragma unroll
            for (int k = 0; k < KT; ++k) {
                const float4 a = *reinterpret_cast<const float4*>(&sfT[k][r0]);
                const float4 b = *reinterpret_cast<const float4*>(&swT[k][tx * 4]);
                acc[0][0] += a.x * b.x; acc[0][1] += a.x * b.y;
                acc[0][2] += a.x * b.z; acc[0][3] += a.x * b.w;
                acc[1][0] += a.y * b.x; acc[1][1] += a.y * b.y;
                acc[1][2] += a.y * b.z; acc[1][3] += a.y * b.w;
                acc[2][0] += a.z * b.x; acc[2][1] += a.z * b.y;
                acc[2][2] += a.z * b.z; acc[2][3] += a.z * b.w;
                acc[3][0] += a.w * b.x; acc[3][1] += a.w * b.y;
                acc[3][2] += a.w * b.z; acc[3][3] += a.w * b.w;
            }
        }
        const int cb = c0 + tx * 4;
        float wnv[4];
        #pragma unroll
        for (int j = 0; j < 4; ++j) wnv[j] = (cb + j < C) ? wn[cb + j] : 1.0f;
        #pragma unroll
        for (int i = 0; i < 4; ++i) {
            const float fni = sfn[r0 + i];
            #pragma unroll
            for (int j = 0; j < 4; ++j) {
                float o;
                if (cb + j < C) {
                    const float denom = fmaxf(fni * wnv[j], 1e-8f);
                    o = S_SCALE * acc[i][j] / denom;
                } else {
                    o = -INFINITY;
                }
                const float mn = fmaxf(m[i], o);
                Z[i] = Z[i] * __expf(m[i] - mn) + __expf(o - mn);
                m[i] = mn;
            }
        }
    }

    #pragma unroll
    for (int i = 0; i < 4; ++i) {
        float mi = m[i], Zi = Z[i];
        #pragma unroll
        for (int off = 1; off < 16; off <<= 1) {
            const float mo = __shfl_xor(mi, off, 64);
            const float Zo = __shfl_xor(Zi, off, 64);
            const float mn = fmaxf(mi, mo);
            Zi = Zi * __expf(mi - mn) + Zo * __expf(mo - mn);
            mi = mn;
        }
        m[i] = mi; Z[i] = Zi;
    }
    if (tx == 0) {
        #pragma unroll
        for (int i = 0; i < 4; ++i) {
            const int row = bx * BM + r0 + i;
            pm[(size_t)row * NSOLD + by] = m[i];
            pZ[(size_t)row * NSOLD + by] = Z[i];
        }
    }
}

// One wave per row: combine np split partials, exact fp32 target logits + margin,
// correct Z, emit per-row loss.
__global__ void finalize_kernel(const float* __restrict__ f, const float* __restrict__ w,
                                const float* __restrict__ fn, const float* __restrict__ wn,
                                const int* __restrict__ pinds, const int* __restrict__ lengths,
                                const float* __restrict__ pm, const float* __restrict__ pZ,
                                float* __restrict__ loss, int np)
{
    const int b = blockIdx.x;
    const int lane = threadIdx.x;

    float mp = -3.0e38f, Zp = 0.0f;
    for (int p = lane; p < np; p += 64) {
        const float mo = pm[(size_t)b * np + p];
        const float Zo = pZ[(size_t)b * np + p];
        const float mn = fmaxf(mp, mo);
        Zp = Zp * __expf(mp - mn) + Zo * __expf(mo - mn);
        mp = mn;
    }
    #pragma unroll
    for (int off = 1; off < 64; off <<= 1) {
        const float mo = __shfl_xor(mp, off, 64);
        const float Zo = __shfl_xor(Zp, off, 64);
        const float mn = fmaxf(mp, mo);
        Zp = Zp * __expf(mp - mn) + Zo * __expf(mo - mn);
        mp = mn;
    }
    const float M = mp;
    const float Ztot = Zp;

    const float4* fp = reinterpret_cast<const float4*>(f + (size_t)b * D);
    const float4 a0 = fp[lane * 2 + 0];
    const float4 a1 = fp[lane * 2 + 1];
    const float fnb = fn[b];
    const int len = lengths[b];

    float opl[LMAX], ops[LMAX];
    int cs[LMAX];
    #pragma unroll
    for (int j = 0; j < LMAX; ++j) {
        const int c = pinds[(size_t)b * LMAX + j];
        cs[j] = c;
        const float4* wp = reinterpret_cast<const float4*>(w + (size_t)c * D);
        const float4 w0 = wp[lane * 2 + 0];
        const float4 w1 = wp[lane * 2 + 1];
        float d = a0.x*w0.x + a0.y*w0.y + a0.z*w0.z + a0.w*w0.w
                + a1.x*w1.x + a1.y*w1.y + a1.z*w1.z + a1.w*w1.w;
        d = wave_sum(d);
        const float cosv = d / fmaxf(fnb * wn[c], 1e-8f);
        const float sine = sqrtf(fminf(fmaxf(1.0f - cosv * cosv, 0.0f), 1.0f));
        float phi = cosv * COS_M - sine * SIN_M;
        phi = (cosv > TH) ? phi : (cosv - MM);
        opl[j] = S_SCALE * cosv;
        ops[j] = S_SCALE * phi;
    }

    float Zc = Ztot;
    for (int j = 0; j < len; ++j) {
        bool dup = false;
        for (int jj = 0; jj < j; ++jj) dup = dup || (cs[jj] == cs[j]);
        if (!dup) Zc += expf(ops[j] - M) - expf(opl[j] - M);
    }
    const float lZ = logf(Zc);
    float acc = 0.0f;
    for (int j = 0; j < len; ++j) acc += (M + lZ - ops[j]);
    const float Lf = (float)len;
    if (lane == 0) loss[b] = acc / (Lf * Lf);
}

__global__ void reduce_kernel(const float* __restrict__ loss, float* __restrict__ out) {
    __shared__ float sdata[256];
    const int t = threadIdx.x;
    float s = 0.0f;
    for (int i = t; i < B; i += 256) s += loss[i];
    sdata[t] = s;
    __syncthreads();
    for (int off = 128; off > 0; off >>= 1) {
        if (t < off) sdata[t] += sdata[t + off];
        __syncthreads();
    }
    if (t == 0) out[0] = sdata[0] * (1.0f / (float)B);
}

} // anonymous namespace

extern "C" void kernel_launch(void* const* d_in, const int* in_sizes, int n_in,
                              void* d_out, int out_size, void* d_ws, size_t ws_size,
                              hipStream_t stream) {
    const float* f   = (const float*)d_in[0];
    // d_in[1] = labels [B,C] — not needed (reconstructed from pinds/lengths)
    const float* w   = (const float*)d_in[2];
    const int* pinds = (const int*)d_in[3];
    const int* lens  = (const int*)d_in[4];
    float* out = (float*)d_out;

    char* ws = (char*)d_ws;
    size_t off = 0;
    auto alloc = [&](size_t bytes) { void* p = ws + off; off = (off + bytes + 255) & ~(size_t)255; return p; };

    float* wn   = (float*)alloc(C * 4);
    float* fn   = (float*)alloc(B * 4);
    float* pm   = (float*)alloc((size_t)B * NPAN * 4);
    float* pZ   = (float*)alloc((size_t)B * NPAN * 4);
    float* loss = (float*)alloc(B * 4);
    f16x8* Ap   = (f16x8*)alloc((size_t)NROWT * KST * CHUNKS * 16);
    f16x8* Bp   = (f16x8*)alloc((size_t)NPAN  * KST * CHUNKS * 16);
    const size_t need = off;

    norm_kernel<<<dim3(B / 4), 256, 0, stream>>>(f, fn, B);
    norm_kernel<<<dim3(C / 4), 256, 0, stream>>>(w, wn, C);

    if (ws_size >= need) {
        pack_a_kernel<<<dim3(NROWT, KST), 256, 0, stream>>>(f, Ap);
        pack_b_kernel<<<dim3(NPAN, KST), 256, 0, stream>>>(w, Bp);
        gemm_mfma_kernel<<<dim3(NROWT, NPAN), 256, 0, stream>>>(Ap, Bp, fn, wn, pm, pZ);
        finalize_kernel<<<dim3(B), 64, 0, stream>>>(f, w, fn, wn, pinds, lens, pm, pZ, loss, NPAN);
    } else {
        gemm_softmax_kernel<<<dim3(B / BM, NSOLD), 256, 0, stream>>>(f, w, fn, wn, pm, pZ);
        finalize_kernel<<<dim3(B), 64, 0, stream>>>(f, w, fn, wn, pinds, lens, pm, pZ, loss, NSOLD);
    }
    reduce_kernel<<<dim3(1), 256, 0, stream>>>(loss, out);
}

// Round 5
// 237.729 us; speedup vs baseline: 2.8928x; 1.0177x over previous
//
#include <hip/hip_runtime.h>
#include <math.h>

namespace {

constexpr int B = 2048;
constexpr int C = 20000;
constexpr int D = 512;
constexpr int LMAX = 8;

// ---------------- MFMA path geometry ----------------
constexpr int BMt = 128, BNt = 128, BKt = 64;
constexpr int NROWT = B / BMt;               // 16 row tiles
constexpr int NPAN  = (C + BNt - 1) / BNt;   // 157 col panels (last has 32 valid)
constexpr int KST   = D / BKt;               // 8 K-steps
constexpr int CHUNKS = 2048;                 // f16x8 (16B) slots per k-step block = 32KB

// ---------------- fp32 fallback geometry ----------------
constexpr int NSOLD = 32;
constexpr int BM = 64, BN = 64, KT = 32, LDP = 68;
constexpr int NTILES = (C + BN - 1) / BN;

constexpr float S_SCALE = 30.0f;
constexpr float COS_M = 0.87758256189037271f;   // cos(0.5)
constexpr float SIN_M = 0.47942553860420301f;   // sin(0.5)
constexpr float TH    = -0.87758256189037271f;  // cos(pi - 0.5)
constexpr float MM    = 0.23971276930210156f;   // sin(pi - 0.5) * 0.5

typedef float f32x16 __attribute__((ext_vector_type(16)));
typedef _Float16 f16x8 __attribute__((ext_vector_type(8)));

__device__ __forceinline__ void mfma_16(f32x16& acc, f16x8 a, f16x8 b) {
    acc = __builtin_amdgcn_mfma_f32_32x32x16_f16(a, b, acc, 0, 0, 0);
}

// async global->LDS, 16B per lane; LDS dest = uniform base + lane*16 (HW).
__device__ __forceinline__ void gload_lds16(const f16x8* gsrc_lane, f16x8* lds_base) {
    __builtin_amdgcn_global_load_lds(
        (const __attribute__((address_space(1))) unsigned int*)gsrc_lane,
        (__attribute__((address_space(3))) unsigned int*)lds_base,
        16, 0, 0);
}

__device__ __forceinline__ float wave_sum(float v) {
    #pragma unroll
    for (int off = 1; off < 64; off <<= 1) v += __shfl_xor(v, off, 64);
    return v;
}

// split x ~= hi + lo in f16 (RNE both stages)
__device__ __forceinline__ void split8(const float4 x0, const float4 x1, f16x8& h, f16x8& l) {
    const float xs[8] = {x0.x, x0.y, x0.z, x0.w, x1.x, x1.y, x1.z, x1.w};
    #pragma unroll
    for (int j = 0; j < 8; ++j) {
        const _Float16 hj = (_Float16)xs[j];
        h[j] = hj;
        l[j] = (_Float16)(xs[j] - (float)hj);
    }
}

// one wave per row: sqrt(sum(x^2)) over D=512
__global__ void norm_kernel(const float* __restrict__ x, float* __restrict__ out, int rows) {
    const int wave = threadIdx.x >> 6, lane = threadIdx.x & 63;
    const int row = blockIdx.x * 4 + wave;
    if (row >= rows) return;
    const float4* p = reinterpret_cast<const float4*>(x + (size_t)row * D);
    const float4 a = p[lane * 2 + 0];
    const float4 b = p[lane * 2 + 1];
    float s = a.x*a.x + a.y*a.y + a.z*a.z + a.w*a.w
            + b.x*b.x + b.y*b.y + b.z*b.z + b.w*b.w;
    s = wave_sum(s);
    if (lane == 0) out[row] = sqrtf(s);
}

// Pack f into fragment-linear f16 hi/lo panels.
// Layout: Ap[rowtile][kstep][chunk][lane] (f16x8). chunk = h*16 + m_frag*4 + k16.
// Slot (chunk,lane): row = m_frag*32+(lane&31), k = k16*16 + (lane>>5)*8 .. +8.
__global__ void pack_a_kernel(const float* __restrict__ f, f16x8* __restrict__ Ap) {
    const int bx = blockIdx.x;   // row tile
    const int s  = blockIdx.y;   // k-step
    const int t  = threadIdx.x;  // 256
    f16x8* blk = Ap + (size_t)(bx * KST + s) * CHUNKS;
    #pragma unroll
    for (int i = 0; i < 4; ++i) {
        const int v = i * 256 + t;           // hi slot id 0..1023
        const int q = v >> 6;                // chunk 0..15 = m_frag*4 + k16
        const int l = v & 63;
        const int row = bx * BMt + (q >> 2) * 32 + (l & 31);
        const int k   = s * BKt + (q & 3) * 16 + (l >> 5) * 8;
        const float4 x0 = *reinterpret_cast<const float4*>(&f[(size_t)row * D + k]);
        const float4 x1 = *reinterpret_cast<const float4*>(&f[(size_t)row * D + k + 4]);
        f16x8 hv, lv;
        split8(x0, x1, hv, lv);
        blk[q * 64 + l] = hv;
        blk[(16 + q) * 64 + l] = lv;
    }
}

// Same for W columns (B operand); zero-fill cols >= C.
__global__ void pack_b_kernel(const float* __restrict__ w, f16x8* __restrict__ Bp) {
    const int pan = blockIdx.x;  // panel
    const int s   = blockIdx.y;  // k-step
    const int t   = threadIdx.x;
    f16x8* blk = Bp + (size_t)(pan * KST + s) * CHUNKS;
    #pragma unroll
    for (int i = 0; i < 4; ++i) {
        const int v = i * 256 + t;
        const int q = v >> 6;
        const int l = v & 63;
        const int col = pan * BNt + (q >> 2) * 32 + (l & 31);
        const int k   = s * BKt + (q & 3) * 16 + (l >> 5) * 8;
        f16x8 hv = (f16x8)0, lv = (f16x8)0;
        if (col < C) {
            const float4 x0 = *reinterpret_cast<const float4*>(&w[(size_t)col * D + k]);
            const float4 x1 = *reinterpret_cast<const float4*>(&w[(size_t)col * D + k + 4]);
            split8(x0, x1, hv, lv);
        }
        blk[q * 64 + l] = hv;
        blk[(16 + q) * 64 + l] = lv;
    }
}

// MFMA GEMM (f16 split-3) + fused online-softmax partials.
// grid = (16 rowtiles, 157 panels), 256 threads (4 waves, 2x2 wave grid, 64x64 per wave).
// Staging via global_load_lds (direct-to-LDS DMA, no VGPR round trip).
__global__ __launch_bounds__(256) void
gemm_mfma_kernel(const f16x8* __restrict__ Ap, const f16x8* __restrict__ Bp,
                 const float* __restrict__ fn, const float* __restrict__ wn,
                 float* __restrict__ pm, float* __restrict__ pZ)
{
    __shared__ f16x8 sA[CHUNKS];   // 32KB
    __shared__ f16x8 sB[CHUNKS];   // 32KB
    const int tid  = threadIdx.x;
    const int lane = tid & 63;
    const int w    = tid >> 6;
    const int wm   = w >> 1;        // 0..1
    const int wnn  = w & 1;         // 0..1
    const int wbase = w * 64;       // wave's slot base within a 256-slot group
    const int bx = blockIdx.x, by = blockIdx.y;
    const f16x8* Ab = Ap + (size_t)(bx * KST) * CHUNKS;
    const f16x8* Bb = Bp + (size_t)(by * KST) * CHUNKS;

    f32x16 acc00, acc01, acc10, acc11;
    #pragma unroll
    for (int i = 0; i < 16; ++i) { acc00[i] = 0.f; acc01[i] = 0.f; acc10[i] = 0.f; acc11[i] = 0.f; }

    for (int s = 0; s < KST; ++s) {
        __syncthreads();   // previous compute done before overwrite
        const f16x8* As = Ab + (size_t)s * CHUNKS;
        const f16x8* Bs = Bb + (size_t)s * CHUNKS;
        #pragma unroll
        for (int i = 0; i < 8; ++i) {
            const int slot = i * 256 + wbase;
            gload_lds16(As + slot + lane, &sA[slot]);
        }
        #pragma unroll
        for (int i = 0; i < 8; ++i) {
            const int slot = i * 256 + wbase;
            gload_lds16(Bs + slot + lane, &sB[slot]);
        }
        __syncthreads();   // drains vmcnt(0): staged data visible
        #pragma unroll
        for (int k16 = 0; k16 < 4; ++k16) {
            const f16x8 ah0 = sA[((wm * 2 + 0) * 4 + k16) * 64 + lane];
            const f16x8 ah1 = sA[((wm * 2 + 1) * 4 + k16) * 64 + lane];
            const f16x8 al0 = sA[(16 + (wm * 2 + 0) * 4 + k16) * 64 + lane];
            const f16x8 al1 = sA[(16 + (wm * 2 + 1) * 4 + k16) * 64 + lane];
            const f16x8 bh0 = sB[((wnn * 2 + 0) * 4 + k16) * 64 + lane];
            const f16x8 bh1 = sB[((wnn * 2 + 1) * 4 + k16) * 64 + lane];
            const f16x8 bl0 = sB[(16 + (wnn * 2 + 0) * 4 + k16) * 64 + lane];
            const f16x8 bl1 = sB[(16 + (wnn * 2 + 1) * 4 + k16) * 64 + lane];
            mfma_16(acc00, ah0, bh0); mfma_16(acc01, ah0, bh1);
            mfma_16(acc10, ah1, bh0); mfma_16(acc11, ah1, bh1);
            mfma_16(acc00, ah0, bl0); mfma_16(acc01, ah0, bl1);
            mfma_16(acc10, ah1, bl0); mfma_16(acc11, ah1, bl1);
            mfma_16(acc00, al0, bh0); mfma_16(acc01, al0, bh1);
            mfma_16(acc10, al1, bh0); mfma_16(acc11, al1, bh1);
        }
    }

    // ---- epilogue: logits -> per-(row, panel) online (max, sumexp) partial ----
    __syncthreads();
    float* sRed = reinterpret_cast<float*>(sA);   // [128 rows][2 wnn][2] = 2KB (reuse)
    const int half = lane >> 5, l31 = lane & 31;
    const int gc0 = by * BNt + wnn * 64 + l31;
    const int gc1 = gc0 + 32;
    const float wnv0 = (gc0 < C) ? wn[gc0] : 1.0f;
    const float wnv1 = (gc1 < C) ? wn[gc1] : 1.0f;

#define EPI_M(A0, A1, M)                                                            \
    {                                                                               \
        _Pragma("unroll")                                                           \
        for (int r = 0; r < 16; ++r) {                                              \
            const int row_in = (r & 3) + 8 * (r >> 2) + 4 * half;                   \
            const int lrow = wm * 64 + (M) * 32 + row_in;                           \
            const float fnv = fn[bx * BMt + lrow];                                  \
            float o0 = (gc0 < C) ? (S_SCALE * (A0)[r] / fmaxf(fnv * wnv0, 1e-8f))   \
                                 : -3.0e38f;                                        \
            float o1 = (gc1 < C) ? (S_SCALE * (A1)[r] / fmaxf(fnv * wnv1, 1e-8f))   \
                                 : -3.0e38f;                                        \
            float mx = fmaxf(o0, o1);                                               \
            _Pragma("unroll")                                                       \
            for (int off = 1; off < 32; off <<= 1)                                  \
                mx = fmaxf(mx, __shfl_xor(mx, off, 64));                            \
            float Zl = __expf(o0 - mx) + __expf(o1 - mx);                           \
            _Pragma("unroll")                                                       \
            for (int off = 1; off < 32; off <<= 1)                                  \
                Zl += __shfl_xor(Zl, off, 64);                                      \
            if (l31 == 0) {                                                         \
                sRed[(lrow * 2 + wnn) * 2 + 0] = mx;                                \
                sRed[(lrow * 2 + wnn) * 2 + 1] = Zl;                                \
            }                                                                       \
        }                                                                           \
    }
    EPI_M(acc00, acc01, 0)
    EPI_M(acc10, acc11, 1)
#undef EPI_M

    __syncthreads();
    if (tid < BMt) {
        const float ma = sRed[(tid * 2 + 0) * 2 + 0], Za = sRed[(tid * 2 + 0) * 2 + 1];
        const float mb = sRed[(tid * 2 + 1) * 2 + 0], Zb = sRed[(tid * 2 + 1) * 2 + 1];
        const float mn = fmaxf(ma, mb);
        const float Zt = Za * __expf(ma - mn) + Zb * __expf(mb - mn);
        pm[(size_t)(bx * BMt + tid) * NPAN + by] = mn;
        pZ[(size_t)(bx * BMt + tid) * NPAN + by] = Zt;
    }
}

// ---------------- fp32 fallback GEMM (proven R2 path) ----------------
__global__ __launch_bounds__(256) void
gemm_softmax_kernel(const float* __restrict__ f, const float* __restrict__ w,
                    const float* __restrict__ fn, const float* __restrict__ wn,
                    float* __restrict__ pm, float* __restrict__ pZ)
{
    __shared__ float sfT[KT][LDP];
    __shared__ float swT[KT][LDP];
    __shared__ float sfn[BM];

    const int tid = threadIdx.x;
    const int bx = blockIdx.x;
    const int by = blockIdx.y;
    const int tx = tid & 15;
    const int tyg = tid >> 4;
    const int r0 = tyg * 4;

    if (tid < BM) sfn[tid] = fn[bx * BM + tid];

    const int lrow = tid >> 3;
    const int k4 = (tid & 7) * 4;

    float m[4], Z[4];
    #pragma unroll
    for (int i = 0; i < 4; ++i) { m[i] = -INFINITY; Z[i] = 0.0f; }

    for (int tile = by; tile < NTILES; tile += NSOLD) {
        const int c0 = tile * BN;
        float acc[4][4];
        #pragma unroll
        for (int i = 0; i < 4; ++i)
            #pragma unroll
            for (int j = 0; j < 4; ++j) acc[i][j] = 0.0f;

        for (int k0 = 0; k0 < D; k0 += KT) {
            __syncthreads();
            {
                const float4 v0 = *reinterpret_cast<const float4*>(
                    &f[(size_t)(bx * BM + lrow) * D + k0 + k4]);
                const float4 v1 = *reinterpret_cast<const float4*>(
                    &f[(size_t)(bx * BM + lrow + 32) * D + k0 + k4]);
                sfT[k4+0][lrow] = v0.x; sfT[k4+1][lrow] = v0.y;
                sfT[k4+2][lrow] = v0.z; sfT[k4+3][lrow] = v0.w;
                sfT[k4+0][lrow+32] = v1.x; sfT[k4+1][lrow+32] = v1.y;
                sfT[k4+2][lrow+32] = v1.z; sfT[k4+3][lrow+32] = v1.w;
            }
            {
                const int c_a = c0 + lrow;
                const int c_b = c0 + lrow + 32;
                float4 v0 = make_float4(0.f,0.f,0.f,0.f);
                float4 v1 = make_float4(0.f,0.f,0.f,0.f);
                if (c_a < C) v0 = *reinterpret_cast<const float4*>(&w[(size_t)c_a * D + k0 + k4]);
                if (c_b < C) v1 = *reinterpret_cast<const float4*>(&w[(size_t)c_b * D + k0 + k4]);
                swT[k4+0][lrow] = v0.x; swT[k4+1][lrow] = v0.y;
                swT[k4+2][lrow] = v0.z; swT[k4+3][lrow] = v0.w;
                swT[k4+0][lrow+32] = v1.x; swT[k4+1][lrow+32] = v1.y;
                swT[k4+2][lrow+32] = v1.z; swT[k4+3][lrow+32] = v1.w;
            }
            __syncthreads();
            #pragma unroll
            for (int k = 0; k < KT; ++k) {
                const float4 a = *reinterpret_cast<const float4*>(&sfT[k][r0]);
                const float4 b = *reinterpret_cast<const float4*>(&swT[k][tx * 4]);
                acc[0][0] += a.x * b.x; acc[0][1] += a.x * b.y;
                acc[0][2] += a.x * b.z; acc[0][3] += a.x * b.w;
                acc[1][0] += a.y * b.x; acc[1][1] += a.y * b.y;
                acc[1][2] += a.y * b.z; acc[1][3] += a.y * b.w;
                acc[2][0] += a.z * b.x; acc[2][1] += a.z * b.y;
                acc[2][2] += a.z * b.z; acc[2][3] += a.z * b.w;
                acc[3][0] += a.w * b.x; acc[3][1] += a.w * b.y;
                acc[3][2] += a.w * b.z; acc[3][3] += a.w * b.w;
            }
        }
        const int cb = c0 + tx * 4;
        float wnv[4];
        #pragma unroll
        for (int j = 0; j < 4; ++j) wnv[j] = (cb + j < C) ? wn[cb + j] : 1.0f;
        #pragma unroll
        for (int i = 0; i < 4; ++i) {
            const float fni = sfn[r0 + i];
            #pragma unroll
            for (int j = 0; j < 4; ++j) {
                float o;
                if (cb + j < C) {
                    const float denom = fmaxf(fni * wnv[j], 1e-8f);
                    o = S_SCALE * acc[i][j] / denom;
                } else {
                    o = -INFINITY;
                }
                const float mn = fmaxf(m[i], o);
                Z[i] = Z[i] * __expf(m[i] - mn) + __expf(o - mn);
                m[i] = mn;
            }
        }
    }

    #pragma unroll
    for (int i = 0; i < 4; ++i) {
        float mi = m[i], Zi = Z[i];
        #pragma unroll
        for (int off = 1; off < 16; off <<= 1) {
            const float mo = __shfl_xor(mi, off, 64);
            const float Zo = __shfl_xor(Zi, off, 64);
            const float mn = fmaxf(mi, mo);
            Zi = Zi * __expf(mi - mn) + Zo * __expf(mo - mn);
            mi = mn;
        }
        m[i] = mi; Z[i] = Zi;
    }
    if (tx == 0) {
        #pragma unroll
        for (int i = 0; i < 4; ++i) {
            const int row = bx * BM + r0 + i;
            pm[(size_t)row * NSOLD + by] = m[i];
            pZ[(size_t)row * NSOLD + by] = Z[i];
        }
    }
}

// One wave per row: combine np split partials, exact fp32 target logits + margin,
// correct Z, emit per-row loss.
__global__ void finalize_kernel(const float* __restrict__ f, const float* __restrict__ w,
                                const float* __restrict__ fn, const float* __restrict__ wn,
                                const int* __restrict__ pinds, const int* __restrict__ lengths,
                                const float* __restrict__ pm, const float* __restrict__ pZ,
                                float* __restrict__ loss, int np)
{
    const int b = blockIdx.x;
    const int lane = threadIdx.x;

    float mp = -3.0e38f, Zp = 0.0f;
    for (int p = lane; p < np; p += 64) {
        const float mo = pm[(size_t)b * np + p];
        const float Zo = pZ[(size_t)b * np + p];
        const float mn = fmaxf(mp, mo);
        Zp = Zp * __expf(mp - mn) + Zo * __expf(mo - mn);
        mp = mn;
    }
    #pragma unroll
    for (int off = 1; off < 64; off <<= 1) {
        const float mo = __shfl_xor(mp, off, 64);
        const float Zo = __shfl_xor(Zp, off, 64);
        const float mn = fmaxf(mp, mo);
        Zp = Zp * __expf(mp - mn) + Zo * __expf(mo - mn);
        mp = mn;
    }
    const float M = mp;
    const float Ztot = Zp;

    const float4* fp = reinterpret_cast<const float4*>(f + (size_t)b * D);
    const float4 a0 = fp[lane * 2 + 0];
    const float4 a1 = fp[lane * 2 + 1];
    const float fnb = fn[b];
    const int len = lengths[b];

    float opl[LMAX], ops[LMAX];
    int cs[LMAX];
    #pragma unroll
    for (int j = 0; j < LMAX; ++j) {
        const int c = pinds[(size_t)b * LMAX + j];
        cs[j] = c;
        const float4* wp = reinterpret_cast<const float4*>(w + (size_t)c * D);
        const float4 w0 = wp[lane * 2 + 0];
        const float4 w1 = wp[lane * 2 + 1];
        float d = a0.x*w0.x + a0.y*w0.y + a0.z*w0.z + a0.w*w0.w
                + a1.x*w1.x + a1.y*w1.y + a1.z*w1.z + a1.w*w1.w;
        d = wave_sum(d);
        const float cosv = d / fmaxf(fnb * wn[c], 1e-8f);
        const float sine = sqrtf(fminf(fmaxf(1.0f - cosv * cosv, 0.0f), 1.0f));
        float phi = cosv * COS_M - sine * SIN_M;
        phi = (cosv > TH) ? phi : (cosv - MM);
        opl[j] = S_SCALE * cosv;
        ops[j] = S_SCALE * phi;
    }

    float Zc = Ztot;
    for (int j = 0; j < len; ++j) {
        bool dup = false;
        for (int jj = 0; jj < j; ++jj) dup = dup || (cs[jj] == cs[j]);
        if (!dup) Zc += expf(ops[j] - M) - expf(opl[j] - M);
    }
    const float lZ = logf(Zc);
    float acc = 0.0f;
    for (int j = 0; j < len; ++j) acc += (M + lZ - ops[j]);
    const float Lf = (float)len;
    if (lane == 0) loss[b] = acc / (Lf * Lf);
}

__global__ void reduce_kernel(const float* __restrict__ loss, float* __restrict__ out) {
    __shared__ float sdata[256];
    const int t = threadIdx.x;
    float s = 0.0f;
    for (int i = t; i < B; i += 256) s += loss[i];
    sdata[t] = s;
    __syncthreads();
    for (int off = 128; off > 0; off >>= 1) {
        if (t < off) sdata[t] += sdata[t + off];
        __syncthreads();
    }
    if (t == 0) out[0] = sdata[0] * (1.0f / (float)B);
}

} // anonymous namespace

extern "C" void kernel_launch(void* const* d_in, const int* in_sizes, int n_in,
                              void* d_out, int out_size, void* d_ws, size_t ws_size,
                              hipStream_t stream) {
    const float* f   = (const float*)d_in[0];
    // d_in[1] = labels [B,C] — not needed (reconstructed from pinds/lengths)
    const float* w   = (const float*)d_in[2];
    const int* pinds = (const int*)d_in[3];
    const int* lens  = (const int*)d_in[4];
    float* out = (float*)d_out;

    char* ws = (char*)d_ws;
    size_t off = 0;
    auto alloc = [&](size_t bytes) { void* p = ws + off; off = (off + bytes + 255) & ~(size_t)255; return p; };

    float* wn   = (float*)alloc(C * 4);
    float* fn   = (float*)alloc(B * 4);
    float* pm   = (float*)alloc((size_t)B * NPAN * 4);
    float* pZ   = (float*)alloc((size_t)B * NPAN * 4);
    float* loss = (float*)alloc(B * 4);
    f16x8* Ap   = (f16x8*)alloc((size_t)NROWT * KST * CHUNKS * 16);
    f16x8* Bp   = (f16x8*)alloc((size_t)NPAN  * KST * CHUNKS * 16);
    const size_t need = off;

    norm_kernel<<<dim3(B / 4), 256, 0, stream>>>(f, fn, B);
    norm_kernel<<<dim3(C / 4), 256, 0, stream>>>(w, wn, C);

    if (ws_size >= need) {
        pack_a_kernel<<<dim3(NROWT, KST), 256, 0, stream>>>(f, Ap);
        pack_b_kernel<<<dim3(NPAN, KST), 256, 0, stream>>>(w, Bp);
        gemm_mfma_kernel<<<dim3(NROWT, NPAN), 256, 0, stream>>>(Ap, Bp, fn, wn, pm, pZ);
        finalize_kernel<<<dim3(B), 64, 0, stream>>>(f, w, fn, wn, pinds, lens, pm, pZ, loss, NPAN);
    } else {
        gemm_softmax_kernel<<<dim3(B / BM, NSOLD), 256, 0, stream>>>(f, w, fn, wn, pm, pZ);
        finalize_kernel<<<dim3(B), 64, 0, stream>>>(f, w, fn, wn, pinds, lens, pm, pZ, loss, NSOLD);
    }
    reduce_kernel<<<dim3(1), 256, 0, stream>>>(loss, out);
}

// Round 6
// 142.021 us; speedup vs baseline: 4.8423x; 1.6739x over previous
//
#include <hip/hip_runtime.h>
#include <math.h>

namespace {

constexpr int B = 2048;
constexpr int C = 20000;
constexpr int D = 512;
constexpr int LMAX = 8;

// ---------------- MFMA path geometry ----------------
constexpr int BMt = 128, BNt = 128, BKt = 64;
constexpr int NROWT = B / BMt;               // 16 row tiles
constexpr int NPAN  = (C + BNt - 1) / BNt;   // 157 col panels (last has 32 valid)
constexpr int KST   = D / BKt;               // 8 K-steps
constexpr int CHUNKS = 1024;                 // f16x8 (16B) slots per k-step block = 16KB

// ---------------- fp32 fallback geometry ----------------
constexpr int NSOLD = 32;
constexpr int BM = 64, BN = 64, KT = 32, LDP = 68;
constexpr int NTILES = (C + BN - 1) / BN;

constexpr float S_SCALE = 30.0f;
constexpr float COS_M = 0.87758256189037271f;   // cos(0.5)
constexpr float SIN_M = 0.47942553860420301f;   // sin(0.5)
constexpr float TH    = -0.87758256189037271f;  // cos(pi - 0.5)
constexpr float MM    = 0.23971276930210156f;   // sin(pi - 0.5) * 0.5

typedef float f32x16 __attribute__((ext_vector_type(16)));
typedef _Float16 f16x8 __attribute__((ext_vector_type(8)));

__device__ __forceinline__ void mfma_16(f32x16& acc, f16x8 a, f16x8 b) {
    acc = __builtin_amdgcn_mfma_f32_32x32x16_f16(a, b, acc, 0, 0, 0);
}

// async global->LDS, 16B per lane; LDS dest = uniform base + lane*16 (HW).
__device__ __forceinline__ void gload_lds16(const f16x8* gsrc_lane, f16x8* lds_base) {
    __builtin_amdgcn_global_load_lds(
        (const __attribute__((address_space(1))) unsigned int*)gsrc_lane,
        (__attribute__((address_space(3))) unsigned int*)lds_base,
        16, 0, 0);
}

__device__ __forceinline__ float wave_sum(float v) {
    #pragma unroll
    for (int off = 1; off < 64; off <<= 1) v += __shfl_xor(v, off, 64);
    return v;
}

// one wave per row: sqrt(sum(x^2)) over D=512
__global__ void norm_kernel(const float* __restrict__ x, float* __restrict__ out, int rows) {
    const int wave = threadIdx.x >> 6, lane = threadIdx.x & 63;
    const int row = blockIdx.x * 4 + wave;
    if (row >= rows) return;
    const float4* p = reinterpret_cast<const float4*>(x + (size_t)row * D);
    const float4 a = p[lane * 2 + 0];
    const float4 b = p[lane * 2 + 1];
    float s = a.x*a.x + a.y*a.y + a.z*a.z + a.w*a.w
            + b.x*b.x + b.y*b.y + b.z*b.z + b.w*b.w;
    s = wave_sum(s);
    if (lane == 0) out[row] = sqrtf(s);
}

// Pack f into fragment-linear f16 panels (single precision level; errors in the
// plain logits only perturb log(Z) — target logits are recomputed in fp32).
// Layout: Ap[rowtile][kstep][chunk][lane] (f16x8). chunk q = m_frag*4 + k16.
// Slot (q,l): row = (q>>2)*32 + (l&31), k = (q&3)*16 + (l>>5)*8 .. +8.
__global__ void pack_a_kernel(const float* __restrict__ f, f16x8* __restrict__ Ap) {
    const int bx = blockIdx.x;   // row tile
    const int s  = blockIdx.y;   // k-step
    const int t  = threadIdx.x;  // 256
    f16x8* blk = Ap + (size_t)(bx * KST + s) * CHUNKS;
    #pragma unroll
    for (int i = 0; i < 4; ++i) {
        const int v = i * 256 + t;           // slot id 0..1023
        const int q = v >> 6;                // chunk = m_frag*4 + k16
        const int l = v & 63;
        const int row = bx * BMt + (q >> 2) * 32 + (l & 31);
        const int k   = s * BKt + (q & 3) * 16 + (l >> 5) * 8;
        const float4 x0 = *reinterpret_cast<const float4*>(&f[(size_t)row * D + k]);
        const float4 x1 = *reinterpret_cast<const float4*>(&f[(size_t)row * D + k + 4]);
        const float xs[8] = {x0.x, x0.y, x0.z, x0.w, x1.x, x1.y, x1.z, x1.w};
        f16x8 hv;
        #pragma unroll
        for (int j = 0; j < 8; ++j) hv[j] = (_Float16)xs[j];
        blk[v] = hv;
    }
}

// Same for W columns (B operand); zero-fill cols >= C.
__global__ void pack_b_kernel(const float* __restrict__ w, f16x8* __restrict__ Bp) {
    const int pan = blockIdx.x;  // panel
    const int s   = blockIdx.y;  // k-step
    const int t   = threadIdx.x;
    f16x8* blk = Bp + (size_t)(pan * KST + s) * CHUNKS;
    #pragma unroll
    for (int i = 0; i < 4; ++i) {
        const int v = i * 256 + t;
        const int q = v >> 6;
        const int l = v & 63;
        const int col = pan * BNt + (q >> 2) * 32 + (l & 31);
        const int k   = s * BKt + (q & 3) * 16 + (l >> 5) * 8;
        f16x8 hv = (f16x8)0;
        if (col < C) {
            const float4 x0 = *reinterpret_cast<const float4*>(&w[(size_t)col * D + k]);
            const float4 x1 = *reinterpret_cast<const float4*>(&w[(size_t)col * D + k + 4]);
            const float xs[8] = {x0.x, x0.y, x0.z, x0.w, x1.x, x1.y, x1.z, x1.w};
            #pragma unroll
            for (int j = 0; j < 8; ++j) hv[j] = (_Float16)xs[j];
        }
        blk[v] = hv;
    }
}

// MFMA GEMM (pure f16) + fused online-softmax partials.
// grid = (16 rowtiles, 157 panels), 256 threads (4 waves, 2x2 wave grid, 64x64 per wave).
// LDS 32KB -> ~4 blocks/CU so blocks hide each other's barrier drains.
__global__ __launch_bounds__(256) void
gemm_mfma_kernel(const f16x8* __restrict__ Ap, const f16x8* __restrict__ Bp,
                 const float* __restrict__ fn, const float* __restrict__ wn,
                 float* __restrict__ pm, float* __restrict__ pZ)
{
    __shared__ f16x8 sA[CHUNKS];   // 16KB
    __shared__ f16x8 sB[CHUNKS];   // 16KB
    const int tid  = threadIdx.x;
    const int lane = tid & 63;
    const int w    = tid >> 6;
    const int wm   = w >> 1;        // 0..1
    const int wnn  = w & 1;         // 0..1
    const int wbase = w * 64;       // wave's slot base within a 256-slot group
    const int bx = blockIdx.x, by = blockIdx.y;
    const f16x8* Ab = Ap + (size_t)(bx * KST) * CHUNKS;
    const f16x8* Bb = Bp + (size_t)(by * KST) * CHUNKS;

    f32x16 acc00, acc01, acc10, acc11;
    #pragma unroll
    for (int i = 0; i < 16; ++i) { acc00[i] = 0.f; acc01[i] = 0.f; acc10[i] = 0.f; acc11[i] = 0.f; }

    for (int s = 0; s < KST; ++s) {
        __syncthreads();   // previous compute done before overwrite
        const f16x8* As = Ab + (size_t)s * CHUNKS;
        const f16x8* Bs = Bb + (size_t)s * CHUNKS;
        #pragma unroll
        for (int i = 0; i < 4; ++i) {
            const int slot = i * 256 + wbase;
            gload_lds16(As + slot + lane, &sA[slot]);
            gload_lds16(Bs + slot + lane, &sB[slot]);
        }
        __syncthreads();   // drains vmcnt(0): staged data visible
        #pragma unroll
        for (int k16 = 0; k16 < 4; ++k16) {
            const f16x8 a0 = sA[((wm * 2 + 0) * 4 + k16) * 64 + lane];
            const f16x8 a1 = sA[((wm * 2 + 1) * 4 + k16) * 64 + lane];
            const f16x8 b0 = sB[((wnn * 2 + 0) * 4 + k16) * 64 + lane];
            const f16x8 b1 = sB[((wnn * 2 + 1) * 4 + k16) * 64 + lane];
            mfma_16(acc00, a0, b0); mfma_16(acc01, a0, b1);
            mfma_16(acc10, a1, b0); mfma_16(acc11, a1, b1);
        }
    }

    // ---- epilogue: logits -> per-(row, panel) online (max, sumexp) partial ----
    __syncthreads();
    float* sRed = reinterpret_cast<float*>(sA);   // [128 rows][2 wnn][2] = 2KB (reuse)
    const int half = lane >> 5, l31 = lane & 31;
    const int gc0 = by * BNt + wnn * 64 + l31;
    const int gc1 = gc0 + 32;
    const float wnv0 = (gc0 < C) ? wn[gc0] : 1.0f;
    const float wnv1 = (gc1 < C) ? wn[gc1] : 1.0f;

#define EPI_M(A0, A1, M)                                                            \
    {                                                                               \
        _Pragma("unroll")                                                           \
        for (int r = 0; r < 16; ++r) {                                              \
            const int row_in = (r & 3) + 8 * (r >> 2) + 4 * half;                   \
            const int lrow = wm * 64 + (M) * 32 + row_in;                           \
            const float fnv = fn[bx * BMt + lrow];                                  \
            float o0 = (gc0 < C) ? (S_SCALE * (A0)[r] / fmaxf(fnv * wnv0, 1e-8f))   \
                                 : -3.0e38f;                                        \
            float o1 = (gc1 < C) ? (S_SCALE * (A1)[r] / fmaxf(fnv * wnv1, 1e-8f))   \
                                 : -3.0e38f;                                        \
            float mx = fmaxf(o0, o1);                                               \
            _Pragma("unroll")                                                       \
            for (int off = 1; off < 32; off <<= 1)                                  \
                mx = fmaxf(mx, __shfl_xor(mx, off, 64));                            \
            float Zl = __expf(o0 - mx) + __expf(o1 - mx);                           \
            _Pragma("unroll")                                                       \
            for (int off = 1; off < 32; off <<= 1)                                  \
                Zl += __shfl_xor(Zl, off, 64);                                      \
            if (l31 == 0) {                                                         \
                sRed[(lrow * 2 + wnn) * 2 + 0] = mx;                                \
                sRed[(lrow * 2 + wnn) * 2 + 1] = Zl;                                \
            }                                                                       \
        }                                                                           \
    }
    EPI_M(acc00, acc01, 0)
    EPI_M(acc10, acc11, 1)
#undef EPI_M

    __syncthreads();
    if (tid < BMt) {
        const float ma = sRed[(tid * 2 + 0) * 2 + 0], Za = sRed[(tid * 2 + 0) * 2 + 1];
        const float mb = sRed[(tid * 2 + 1) * 2 + 0], Zb = sRed[(tid * 2 + 1) * 2 + 1];
        const float mn = fmaxf(ma, mb);
        const float Zt = Za * __expf(ma - mn) + Zb * __expf(mb - mn);
        pm[(size_t)(bx * BMt + tid) * NPAN + by] = mn;
        pZ[(size_t)(bx * BMt + tid) * NPAN + by] = Zt;
    }
}

// ---------------- fp32 fallback GEMM (proven R2 path) ----------------
__global__ __launch_bounds__(256) void
gemm_softmax_kernel(const float* __restrict__ f, const float* __restrict__ w,
                    const float* __restrict__ fn, const float* __restrict__ wn,
                    float* __restrict__ pm, float* __restrict__ pZ)
{
    __shared__ float sfT[KT][LDP];
    __shared__ float swT[KT][LDP];
    __shared__ float sfn[BM];

    const int tid = threadIdx.x;
    const int bx = blockIdx.x;
    const int by = blockIdx.y;
    const int tx = tid & 15;
    const int tyg = tid >> 4;
    const int r0 = tyg * 4;

    if (tid < BM) sfn[tid] = fn[bx * BM + tid];

    const int lrow = tid >> 3;
    const int k4 = (tid & 7) * 4;

    float m[4], Z[4];
    #pragma unroll
    for (int i = 0; i < 4; ++i) { m[i] = -INFINITY; Z[i] = 0.0f; }

    for (int tile = by; tile < NTILES; tile += NSOLD) {
        const int c0 = tile * BN;
        float acc[4][4];
        #pragma unroll
        for (int i = 0; i < 4; ++i)
            #pragma unroll
            for (int j = 0; j < 4; ++j) acc[i][j] = 0.0f;

        for (int k0 = 0; k0 < D; k0 += KT) {
            __syncthreads();
            {
                const float4 v0 = *reinterpret_cast<const float4*>(
                    &f[(size_t)(bx * BM + lrow) * D + k0 + k4]);
                const float4 v1 = *reinterpret_cast<const float4*>(
                    &f[(size_t)(bx * BM + lrow + 32) * D + k0 + k4]);
                sfT[k4+0][lrow] = v0.x; sfT[k4+1][lrow] = v0.y;
                sfT[k4+2][lrow] = v0.z; sfT[k4+3][lrow] = v0.w;
                sfT[k4+0][lrow+32] = v1.x; sfT[k4+1][lrow+32] = v1.y;
                sfT[k4+2][lrow+32] = v1.z; sfT[k4+3][lrow+32] = v1.w;
            }
            {
                const int c_a = c0 + lrow;
                const int c_b = c0 + lrow + 32;
                float4 v0 = make_float4(0.f,0.f,0.f,0.f);
                float4 v1 = make_float4(0.f,0.f,0.f,0.f);
                if (c_a < C) v0 = *reinterpret_cast<const float4*>(&w[(size_t)c_a * D + k0 + k4]);
                if (c_b < C) v1 = *reinterpret_cast<const float4*>(&w[(size_t)c_b * D + k0 + k4]);
                swT[k4+0][lrow] = v0.x; swT[k4+1][lrow] = v0.y;
                swT[k4+2][lrow] = v0.z; swT[k4+3][lrow] = v0.w;
                swT[k4+0][lrow+32] = v1.x; swT[k4+1][lrow+32] = v1.y;
                swT[k4+2][lrow+32] = v1.z; swT[k4+3][lrow+32] = v1.w;
            }
            __syncthreads();
            #pragma unroll
            for (int k = 0; k < KT; ++k) {
                const float4 a = *reinterpret_cast<const float4*>(&sfT[k][r0]);
                const float4 b = *reinterpret_cast<const float4*>(&swT[k][tx * 4]);
                acc[0][0] += a.x * b.x; acc[0][1] += a.x * b.y;
                acc[0][2] += a.x * b.z; acc[0][3] += a.x * b.w;
                acc[1][0] += a.y * b.x; acc[1][1] += a.y * b.y;
                acc[1][2] += a.y * b.z; acc[1][3] += a.y * b.w;
                acc[2][0] += a.z * b.x; acc[2][1] += a.z * b.y;
                acc[2][2] += a.z * b.z; acc[2][3] += a.z * b.w;
                acc[3][0] += a.w * b.x; acc[3][1] += a.w * b.y;
                acc[3][2] += a.w * b.z; acc[3][3] += a.w * b.w;
            }
        }
        const int cb = c0 + tx * 4;
        float wnv[4];
        #pragma unroll
        for (int j = 0; j < 4; ++j) wnv[j] = (cb + j < C) ? wn[cb + j] : 1.0f;
        #pragma unroll
        for (int i = 0; i < 4; ++i) {
            const float fni = sfn[r0 + i];
            #pragma unroll
            for (int j = 0; j < 4; ++j) {
                float o;
                if (cb + j < C) {
                    const float denom = fmaxf(fni * wnv[j], 1e-8f);
                    o = S_SCALE * acc[i][j] / denom;
                } else {
                    o = -INFINITY;
                }
                const float mn = fmaxf(m[i], o);
                Z[i] = Z[i] * __expf(m[i] - mn) + __expf(o - mn);
                m[i] = mn;
            }
        }
    }

    #pragma unroll
    for (int i = 0; i < 4; ++i) {
        float mi = m[i], Zi = Z[i];
        #pragma unroll
        for (int off = 1; off < 16; off <<= 1) {
            const float mo = __shfl_xor(mi, off, 64);
            const float Zo = __shfl_xor(Zi, off, 64);
            const float mn = fmaxf(mi, mo);
            Zi = Zi * __expf(mi - mn) + Zo * __expf(mo - mn);
            mi = mn;
        }
        m[i] = mi; Z[i] = Zi;
    }
    if (tx == 0) {
        #pragma unroll
        for (int i = 0; i < 4; ++i) {
            const int row = bx * BM + r0 + i;
            pm[(size_t)row * NSOLD + by] = m[i];
            pZ[(size_t)row * NSOLD + by] = Z[i];
        }
    }
}

// One wave per row: combine np split partials, exact fp32 target logits + margin,
// correct Z, emit per-row loss.
__global__ void finalize_kernel(const float* __restrict__ f, const float* __restrict__ w,
                                const float* __restrict__ fn, const float* __restrict__ wn,
                                const int* __restrict__ pinds, const int* __restrict__ lengths,
                                const float* __restrict__ pm, const float* __restrict__ pZ,
                                float* __restrict__ loss, int np)
{
    const int b = blockIdx.x;
    const int lane = threadIdx.x;

    float mp = -3.0e38f, Zp = 0.0f;
    for (int p = lane; p < np; p += 64) {
        const float mo = pm[(size_t)b * np + p];
        const float Zo = pZ[(size_t)b * np + p];
        const float mn = fmaxf(mp, mo);
        Zp = Zp * __expf(mp - mn) + Zo * __expf(mo - mn);
        mp = mn;
    }
    #pragma unroll
    for (int off = 1; off < 64; off <<= 1) {
        const float mo = __shfl_xor(mp, off, 64);
        const float Zo = __shfl_xor(Zp, off, 64);
        const float mn = fmaxf(mp, mo);
        Zp = Zp * __expf(mp - mn) + Zo * __expf(mo - mn);
        mp = mn;
    }
    const float M = mp;
    const float Ztot = Zp;

    const float4* fp = reinterpret_cast<const float4*>(f + (size_t)b * D);
    const float4 a0 = fp[lane * 2 + 0];
    const float4 a1 = fp[lane * 2 + 1];
    const float fnb = fn[b];
    const int len = lengths[b];

    float opl[LMAX], ops[LMAX];
    int cs[LMAX];
    #pragma unroll
    for (int j = 0; j < LMAX; ++j) {
        const int c = pinds[(size_t)b * LMAX + j];
        cs[j] = c;
        const float4* wp = reinterpret_cast<const float4*>(w + (size_t)c * D);
        const float4 w0 = wp[lane * 2 + 0];
        const float4 w1 = wp[lane * 2 + 1];
        float d = a0.x*w0.x + a0.y*w0.y + a0.z*w0.z + a0.w*w0.w
                + a1.x*w1.x + a1.y*w1.y + a1.z*w1.z + a1.w*w1.w;
        d = wave_sum(d);
        const float cosv = d / fmaxf(fnb * wn[c], 1e-8f);
        const float sine = sqrtf(fminf(fmaxf(1.0f - cosv * cosv, 0.0f), 1.0f));
        float phi = cosv * COS_M - sine * SIN_M;
        phi = (cosv > TH) ? phi : (cosv - MM);
        opl[j] = S_SCALE * cosv;
        ops[j] = S_SCALE * phi;
    }

    float Zc = Ztot;
    for (int j = 0; j < len; ++j) {
        bool dup = false;
        for (int jj = 0; jj < j; ++jj) dup = dup || (cs[jj] == cs[j]);
        if (!dup) Zc += expf(ops[j] - M) - expf(opl[j] - M);
    }
    const float lZ = logf(Zc);
    float acc = 0.0f;
    for (int j = 0; j < len; ++j) acc += (M + lZ - ops[j]);
    const float Lf = (float)len;
    if (lane == 0) loss[b] = acc / (Lf * Lf);
}

__global__ void reduce_kernel(const float* __restrict__ loss, float* __restrict__ out) {
    __shared__ float sdata[256];
    const int t = threadIdx.x;
    float s = 0.0f;
    for (int i = t; i < B; i += 256) s += loss[i];
    sdata[t] = s;
    __syncthreads();
    for (int off = 128; off > 0; off >>= 1) {
        if (t < off) sdata[t] += sdata[t + off];
        __syncthreads();
    }
    if (t == 0) out[0] = sdata[0] * (1.0f / (float)B);
}

} // anonymous namespace

extern "C" void kernel_launch(void* const* d_in, const int* in_sizes, int n_in,
                              void* d_out, int out_size, void* d_ws, size_t ws_size,
                              hipStream_t stream) {
    const float* f   = (const float*)d_in[0];
    // d_in[1] = labels [B,C] — not needed (reconstructed from pinds/lengths)
    const float* w   = (const float*)d_in[2];
    const int* pinds = (const int*)d_in[3];
    const int* lens  = (const int*)d_in[4];
    float* out = (float*)d_out;

    char* ws = (char*)d_ws;
    size_t off = 0;
    auto alloc = [&](size_t bytes) { void* p = ws + off; off = (off + bytes + 255) & ~(size_t)255; return p; };

    float* wn   = (float*)alloc(C * 4);
    float* fn   = (float*)alloc(B * 4);
    float* pm   = (float*)alloc((size_t)B * NPAN * 4);
    float* pZ   = (float*)alloc((size_t)B * NPAN * 4);
    float* loss = (float*)alloc(B * 4);
    f16x8* Ap   = (f16x8*)alloc((size_t)NROWT * KST * CHUNKS * 16);
    f16x8* Bp   = (f16x8*)alloc((size_t)NPAN  * KST * CHUNKS * 16);
    const size_t need = off;

    norm_kernel<<<dim3(B / 4), 256, 0, stream>>>(f, fn, B);
    norm_kernel<<<dim3(C / 4), 256, 0, stream>>>(w, wn, C);

    if (ws_size >= need) {
        pack_a_kernel<<<dim3(NROWT, KST), 256, 0, stream>>>(f, Ap);
        pack_b_kernel<<<dim3(NPAN, KST), 256, 0, stream>>>(w, Bp);
        gemm_mfma_kernel<<<dim3(NROWT, NPAN), 256, 0, stream>>>(Ap, Bp, fn, wn, pm, pZ);
        finalize_kernel<<<dim3(B), 64, 0, stream>>>(f, w, fn, wn, pinds, lens, pm, pZ, loss, NPAN);
    } else {
        gemm_softmax_kernel<<<dim3(B / BM, NSOLD), 256, 0, stream>>>(f, w, fn, wn, pm, pZ);
        finalize_kernel<<<dim3(B), 64, 0, stream>>>(f, w, fn, wn, pinds, lens, pm, pZ, loss, NSOLD);
    }
    reduce_kernel<<<dim3(1), 256, 0, stream>>>(loss, out);
}

// Round 7
// 130.230 us; speedup vs baseline: 5.2807x; 1.0905x over previous
//
#include <hip/hip_runtime.h>
#include <math.h>

namespace {

constexpr int B = 2048;
constexpr int C = 20000;
constexpr int D = 512;
constexpr int LMAX = 8;

constexpr int BMt = 128, BNt = 128, BKt = 64;
constexpr int NROWT = B / BMt;               // 16 row tiles
constexpr int NPAN  = (C + BNt - 1) / BNt;   // 157 col panels (last has 32 valid)
constexpr int KST   = D / BKt;               // 8 K-steps
constexpr int CHUNKS = 1024;                 // f16x8 (16B) slots per (tile,kstep) = 16KB

constexpr float S_SCALE = 30.0f;
constexpr float COS_M = 0.87758256189037271f;   // cos(0.5)
constexpr float SIN_M = 0.47942553860420301f;   // sin(0.5)
constexpr float TH    = -0.87758256189037271f;  // cos(pi - 0.5)
constexpr float MM    = 0.23971276930210156f;   // sin(pi - 0.5) * 0.5
constexpr float MFIX  = 30.0f;                  // fixed softmax shift: |logits| <= 30

typedef float f32x16 __attribute__((ext_vector_type(16)));
typedef _Float16 f16x8 __attribute__((ext_vector_type(8)));

__device__ __forceinline__ void mfma_16(f32x16& acc, f16x8 a, f16x8 b) {
    acc = __builtin_amdgcn_mfma_f32_32x32x16_f16(a, b, acc, 0, 0, 0);
}

__device__ __forceinline__ float wave_sum(float v) {
    #pragma unroll
    for (int off = 1; off < 64; off <<= 1) v += __shfl_xor(v, off, 64);
    return v;
}

// one wave per row: sqrt(sum(x^2)) over D=512
__global__ void norm_kernel(const float* __restrict__ x, float* __restrict__ out, int rows) {
    const int wave = threadIdx.x >> 6, lane = threadIdx.x & 63;
    const int row = blockIdx.x * 4 + wave;
    if (row >= rows) return;
    const float4* p = reinterpret_cast<const float4*>(x + (size_t)row * D);
    const float4 a = p[lane * 2 + 0];
    const float4 b = p[lane * 2 + 1];
    float s = a.x*a.x + a.y*a.y + a.z*a.z + a.w*a.w
            + b.x*b.x + b.y*b.y + b.z*b.z + b.w*b.w;
    s = wave_sum(s);
    if (lane == 0) out[row] = sqrtf(s);
}

// Pack f into fragment-linear f16 panels.
// Layout: Ap[rowtile][kstep][chunk][lane] (f16x8). chunk q = m_frag*4 + k16.
// Slot (q,l): row = (q>>2)*32 + (l&31), k = (q&3)*16 + (l>>5)*8 .. +8.
__global__ void pack_a_kernel(const float* __restrict__ f, f16x8* __restrict__ Ap) {
    const int bx = blockIdx.x;   // row tile
    const int s  = blockIdx.y;   // k-step
    const int t  = threadIdx.x;  // 256
    f16x8* blk = Ap + (size_t)(bx * KST + s) * CHUNKS;
    #pragma unroll
    for (int i = 0; i < 4; ++i) {
        const int v = i * 256 + t;           // slot id 0..1023
        const int q = v >> 6;                // chunk = m_frag*4 + k16
        const int l = v & 63;
        const int row = bx * BMt + (q >> 2) * 32 + (l & 31);
        const int k   = s * BKt + (q & 3) * 16 + (l >> 5) * 8;
        const float4 x0 = *reinterpret_cast<const float4*>(&f[(size_t)row * D + k]);
        const float4 x1 = *reinterpret_cast<const float4*>(&f[(size_t)row * D + k + 4]);
        const float xs[8] = {x0.x, x0.y, x0.z, x0.w, x1.x, x1.y, x1.z, x1.w};
        f16x8 hv;
        #pragma unroll
        for (int j = 0; j < 8; ++j) hv[j] = (_Float16)xs[j];
        blk[v] = hv;
    }
}

// Same for W columns (B operand); zero-fill cols >= C.
__global__ void pack_b_kernel(const float* __restrict__ w, f16x8* __restrict__ Bp) {
    const int pan = blockIdx.x;  // panel
    const int s   = blockIdx.y;  // k-step
    const int t   = threadIdx.x;
    f16x8* blk = Bp + (size_t)(pan * KST + s) * CHUNKS;
    #pragma unroll
    for (int i = 0; i < 4; ++i) {
        const int v = i * 256 + t;
        const int q = v >> 6;
        const int l = v & 63;
        const int col = pan * BNt + (q >> 2) * 32 + (l & 31);
        const int k   = s * BKt + (q & 3) * 16 + (l >> 5) * 8;
        f16x8 hv = (f16x8)0;
        if (col < C) {
            const float4 x0 = *reinterpret_cast<const float4*>(&w[(size_t)col * D + k]);
            const float4 x1 = *reinterpret_cast<const float4*>(&w[(size_t)col * D + k + 4]);
            const float xs[8] = {x0.x, x0.y, x0.z, x0.w, x1.x, x1.y, x1.z, x1.w};
            #pragma unroll
            for (int j = 0; j < 8; ++j) hv[j] = (_Float16)xs[j];
        }
        blk[v] = hv;
    }
}

// MFMA GEMM (pure f16), fragments streamed DIRECTLY global->VGPR (no LDS, no
// barriers in the main loop; reuse served by L1/L2). Fused fixed-shift
// softmax-denominator partial: pZ[row,panel] = sum_cols exp(o - 30).
// grid = (16 rowtiles, 157 panels), 256 threads (4 waves, 2x2, 64x64 per wave).
__global__ __launch_bounds__(256) void
gemm_mfma_kernel(const f16x8* __restrict__ Ap, const f16x8* __restrict__ Bp,
                 const float* __restrict__ fn, const float* __restrict__ wn,
                 float* __restrict__ pZ)
{
    __shared__ float sifn[BMt];       // S/fn per row
    __shared__ float sRed[BMt][2];
    const int tid  = threadIdx.x;
    const int lane = tid & 63;
    const int w    = tid >> 6;
    const int wm   = w >> 1;        // 0..1
    const int wnn  = w & 1;         // 0..1
    const int bx = blockIdx.x, by = blockIdx.y;

    if (tid < BMt) sifn[tid] = S_SCALE / fmaxf(fn[bx * BMt + tid], 1e-8f);

    // wave-local fragment bases (chunk = m_frag*4 + k16, 64 lanes per chunk)
    const f16x8* Aw = Ap + (size_t)bx * KST * CHUNKS + wm * 512 + lane;
    const f16x8* Bw = Bp + (size_t)by * KST * CHUNKS + wnn * 512 + lane;

    f32x16 acc00, acc01, acc10, acc11;
    #pragma unroll
    for (int i = 0; i < 16; ++i) { acc00[i] = 0.f; acc01[i] = 0.f; acc10[i] = 0.f; acc11[i] = 0.f; }

    #pragma unroll 2
    for (int s = 0; s < KST; ++s) {
        const f16x8* As = Aw + s * CHUNKS;
        const f16x8* Bs = Bw + s * CHUNKS;
        #pragma unroll
        for (int k16 = 0; k16 < 4; ++k16) {
            const f16x8 a0 = As[k16 * 64];
            const f16x8 a1 = As[256 + k16 * 64];
            const f16x8 b0 = Bs[k16 * 64];
            const f16x8 b1 = Bs[256 + k16 * 64];
            mfma_16(acc00, a0, b0); mfma_16(acc01, a0, b1);
            mfma_16(acc10, a1, b0); mfma_16(acc11, a1, b1);
        }
    }

    // ---- epilogue: per-(row, panel) partial Z = sum exp(o - 30), o = 30*cos ----
    __syncthreads();   // sifn visible
    const int half = lane >> 5, l31 = lane & 31;
    const int gc0 = by * BNt + wnn * 64 + l31;
    const int gc1 = gc0 + 32;
    const bool v0 = gc0 < C, v1 = gc1 < C;
    const float iw0 = v0 ? (1.0f / fmaxf(wn[gc0], 1e-8f)) : 0.0f;
    const float iw1 = v1 ? (1.0f / fmaxf(wn[gc1], 1e-8f)) : 0.0f;

#define EPI_M(A0, A1, M)                                                        \
    {                                                                           \
        _Pragma("unroll")                                                       \
        for (int r = 0; r < 16; ++r) {                                          \
            const int lrow = wm * 64 + (M) * 32 + (r & 3) + 8 * (r >> 2) + 4 * half; \
            const float ifn = sifn[lrow];                                       \
            const float c0 = ifn * iw0;                                         \
            const float c1 = ifn * iw1;                                         \
            const float e0 = v0 ? __expf(fmaf((A0)[r], c0, -MFIX)) : 0.0f;      \
            const float e1 = v1 ? __expf(fmaf((A1)[r], c1, -MFIX)) : 0.0f;      \
            float Zl = e0 + e1;                                                 \
            _Pragma("unroll")                                                   \
            for (int off = 1; off < 32; off <<= 1)                              \
                Zl += __shfl_xor(Zl, off, 64);                                  \
            if (l31 == 0) sRed[lrow][wnn] = Zl;                                 \
        }                                                                       \
    }
    EPI_M(acc00, acc01, 0)
    EPI_M(acc10, acc11, 1)
#undef EPI_M

    __syncthreads();
    if (tid < BMt) {
        pZ[(size_t)(bx * BMt + tid) * NPAN + by] = sRed[tid][0] + sRed[tid][1];
    }
}

// One wave per row: sum the NPAN partials (fixed shift M=30), exact fp32 target
// logits + ArcFace margin, correct Z, emit per-row loss.
__global__ void finalize_kernel(const float* __restrict__ f, const float* __restrict__ w,
                                const float* __restrict__ fn, const float* __restrict__ wn,
                                const int* __restrict__ pinds, const int* __restrict__ lengths,
                                const float* __restrict__ pZ, float* __restrict__ loss)
{
    const int b = blockIdx.x;
    const int lane = threadIdx.x;

    float Zp = 0.0f;
    for (int p = lane; p < NPAN; p += 64) Zp += pZ[(size_t)b * NPAN + p];
    Zp = wave_sum(Zp);

    const float4* fp = reinterpret_cast<const float4*>(f + (size_t)b * D);
    const float4 a0 = fp[lane * 2 + 0];
    const float4 a1 = fp[lane * 2 + 1];
    const float fnb = fn[b];
    const int len = lengths[b];

    float opl[LMAX], ops[LMAX];
    int cs[LMAX];
    #pragma unroll
    for (int j = 0; j < LMAX; ++j) {
        const int c = pinds[(size_t)b * LMAX + j];
        cs[j] = c;
        const float4* wp = reinterpret_cast<const float4*>(w + (size_t)c * D);
        const float4 w0 = wp[lane * 2 + 0];
        const float4 w1 = wp[lane * 2 + 1];
        float d = a0.x*w0.x + a0.y*w0.y + a0.z*w0.z + a0.w*w0.w
                + a1.x*w1.x + a1.y*w1.y + a1.z*w1.z + a1.w*w1.w;
        d = wave_sum(d);
        const float cosv = d / fmaxf(fnb * wn[c], 1e-8f);
        const float sine = sqrtf(fminf(fmaxf(1.0f - cosv * cosv, 0.0f), 1.0f));
        float phi = cosv * COS_M - sine * SIN_M;
        phi = (cosv > TH) ? phi : (cosv - MM);
        opl[j] = S_SCALE * cosv;
        ops[j] = S_SCALE * phi;
    }

    // correct Z for unique positive classes (margin applied), then ragged CE
    float Zc = Zp;
    for (int j = 0; j < len; ++j) {
        bool dup = false;
        for (int jj = 0; jj < j; ++jj) dup = dup || (cs[jj] == cs[j]);
        if (!dup) Zc += expf(ops[j] - MFIX) - expf(opl[j] - MFIX);
    }
    const float lZ = logf(Zc);
    float acc = 0.0f;
    for (int j = 0; j < len; ++j) acc += (MFIX + lZ - ops[j]);
    const float Lf = (float)len;
    if (lane == 0) loss[b] = acc / (Lf * Lf);
}

__global__ void reduce_kernel(const float* __restrict__ loss, float* __restrict__ out) {
    __shared__ float sdata[256];
    const int t = threadIdx.x;
    float s = 0.0f;
    for (int i = t; i < B; i += 256) s += loss[i];
    sdata[t] = s;
    __syncthreads();
    for (int off = 128; off > 0; off >>= 1) {
        if (t < off) sdata[t] += sdata[t + off];
        __syncthreads();
    }
    if (t == 0) out[0] = sdata[0] * (1.0f / (float)B);
}

} // anonymous namespace

extern "C" void kernel_launch(void* const* d_in, const int* in_sizes, int n_in,
                              void* d_out, int out_size, void* d_ws, size_t ws_size,
                              hipStream_t stream) {
    const float* f   = (const float*)d_in[0];
    // d_in[1] = labels [B,C] — not needed (reconstructed from pinds/lengths)
    const float* w   = (const float*)d_in[2];
    const int* pinds = (const int*)d_in[3];
    const int* lens  = (const int*)d_in[4];
    float* out = (float*)d_out;

    char* ws = (char*)d_ws;
    size_t off = 0;
    auto alloc = [&](size_t bytes) { void* p = ws + off; off = (off + bytes + 255) & ~(size_t)255; return p; };

    float* wn   = (float*)alloc(C * 4);
    float* fn   = (float*)alloc(B * 4);
    float* pZ   = (float*)alloc((size_t)B * NPAN * 4);
    float* loss = (float*)alloc(B * 4);
    f16x8* Ap   = (f16x8*)alloc((size_t)NROWT * KST * CHUNKS * 16);
    f16x8* Bp   = (f16x8*)alloc((size_t)NPAN  * KST * CHUNKS * 16);

    norm_kernel<<<dim3(B / 4), 256, 0, stream>>>(f, fn, B);
    norm_kernel<<<dim3(C / 4), 256, 0, stream>>>(w, wn, C);
    pack_a_kernel<<<dim3(NROWT, KST), 256, 0, stream>>>(f, Ap);
    pack_b_kernel<<<dim3(NPAN, KST), 256, 0, stream>>>(w, Bp);
    gemm_mfma_kernel<<<dim3(NROWT, NPAN), 256, 0, stream>>>(Ap, Bp, fn, wn, pZ);
    finalize_kernel<<<dim3(B), 64, 0, stream>>>(f, w, fn, wn, pinds, lens, pZ, loss);
    reduce_kernel<<<dim3(1), 256, 0, stream>>>(loss, out);
}